// Round 1
// 531.847 us; speedup vs baseline: 1.0711x; 1.0711x over previous
//
#include <hip/hip_runtime.h>

// (B,S,E,L) = (4, 4096, 64, 3)
#define SEQ  4096
#define EMB  64
#define NB   4
#define XROW 4097

// XOR swizzle for [row][64] bf16 tiles accessed as 16B chunks (chunk = 8 shorts).
// Row stride is 128 B == 32 banks, so bank index must come from the chunk bits:
// spread chunks across the 8 slots by XORing with row&7.  Apply on BOTH sides.
#define SW(r, c) ((r) * 64 + (((c) ^ ((r) & 7)) << 3))

typedef unsigned short ushort_t;
typedef __attribute__((ext_vector_type(8))) short short8;
typedef __attribute__((ext_vector_type(4))) float floatx4;

union U8 { uint4 u; short8 s8; };

// fp32 -> bf16 round-to-nearest-even
__device__ __forceinline__ ushort_t f2bf(float f) {
    union { float f; unsigned int u; } v; v.f = f;
    unsigned int r = v.u + 0x7FFFu + ((v.u >> 16) & 1u);
    return (ushort_t)(r >> 16);
}
__device__ __forceinline__ uint2 pack4bf(float a, float b, float c, float d) {
    uint2 p;
    p.x = (unsigned)f2bf(a) | ((unsigned)f2bf(b) << 16);
    p.y = (unsigned)f2bf(c) | ((unsigned)f2bf(d) << 16);
    return p;
}

// ---------------------------------------------------------------------------
// prep: rmT[e][f] = bf16(rm[f][e]) for e<63, 0 for e==63.  [64][4096] bf16
// Also initializes out[b] = offset (runs first in the stream).
// ---------------------------------------------------------------------------
__global__ __launch_bounds__(256) void prep_rmt(const float* __restrict__ rm,
                                                ushort_t* __restrict__ rmT,
                                                float* __restrict__ out,
                                                const float* __restrict__ offset) {
    if (blockIdx.x == 0 && threadIdx.x < NB) out[threadIdx.x] = offset[0];
    int o = (blockIdx.x * 256 + threadIdx.x) * 4;
    int e = o >> 12;
    int f = o & 4095;
    alignas(8) ushort_t t[4];
    t[0] = f2bf((e < 63) ? rm[(size_t)(f + 0) * 63 + e] : 0.f);
    t[1] = f2bf((e < 63) ? rm[(size_t)(f + 1) * 63 + e] : 0.f);
    t[2] = f2bf((e < 63) ? rm[(size_t)(f + 2) * 63 + e] : 0.f);
    t[3] = f2bf((e < 63) ? rm[(size_t)(f + 3) * 63 + e] : 0.f);
    *(uint2*)&rmT[o] = *(uint2*)t;
}

// ---------------------------------------------------------------------------
// Projection via MFMA, 512 threads: two wave-groups split the K range
// (2048 each), private LDS buffers, partial accumulators combined via LDS.
// av[row][e] = sum_f x[row][f]*rm[f][e] (e<63), av[row][63] = x[row][4096].
// ---------------------------------------------------------------------------
__global__ __launch_bounds__(512) void proj_mfma(const float* __restrict__ x,
        const ushort_t* __restrict__ rmT, float* __restrict__ av) {
    __shared__ ushort_t xs[2][64 * 64];   // per-half [row][f] bf16 (swizzled)
    __shared__ ushort_t rs[2][64 * 64];   // per-half [e][f]   bf16 (swizzled)
    const int tid = threadIdx.x;
    const int row0 = blockIdx.x * 64;
    const int w = tid >> 6, l = tid & 63;
    const int wg = w >> 2;                 // K-half (0/1)
    const int wq = w & 3;                  // m-subtile within half
    const int t4 = tid & 255;
    const int srow = t4 >> 2, sc = (t4 & 3) * 16;
    const int c0 = (t4 & 3) * 2;           // chunk index of this thread's 16B pair
    const int kbase = wg * 2048;
    const int quad = l >> 4, q16 = l & 15;

    floatx4 acc[4];
    #pragma unroll
    for (int i = 0; i < 4; ++i) acc[i] = (floatx4){0.f, 0.f, 0.f, 0.f};

    // prefetch tile 0 of this half
    float px[16];
    short8 pr0, pr1;
    {
        const float* xp = x + (size_t)(row0 + srow) * XROW + kbase + sc;
        #pragma unroll
        for (int i = 0; i < 16; ++i) px[i] = xp[i];
        const ushort_t* rp = rmT + (size_t)srow * SEQ + kbase + sc;
        pr0 = *(const short8*)&rp[0];
        pr1 = *(const short8*)&rp[8];
    }

    for (int k0 = 0; k0 < 2048; k0 += 64) {
        __syncthreads();
        {
            alignas(16) ushort_t tmp[16];
            #pragma unroll
            for (int i = 0; i < 16; ++i) tmp[i] = f2bf(px[i]);
            *(short8*)&xs[wg][SW(srow, c0)]     = *(short8*)&tmp[0];
            *(short8*)&xs[wg][SW(srow, c0 + 1)] = *(short8*)&tmp[8];
            *(short8*)&rs[wg][SW(srow, c0)]     = pr0;
            *(short8*)&rs[wg][SW(srow, c0 + 1)] = pr1;
        }
        __syncthreads();
        if (k0 + 64 < 2048) {   // prefetch next tile during compute
            const float* xp = x + (size_t)(row0 + srow) * XROW + kbase + k0 + 64 + sc;
            #pragma unroll
            for (int i = 0; i < 16; ++i) px[i] = xp[i];
            const ushort_t* rp = rmT + (size_t)srow * SEQ + kbase + k0 + 64 + sc;
            pr0 = *(const short8*)&rp[0];
            pr1 = *(const short8*)&rp[8];
        }
        #pragma unroll
        for (int ksp = 0; ksp < 2; ++ksp) {
            short8 a = *(short8*)&xs[wg][SW(wq * 16 + q16, ksp * 4 + quad)];
            #pragma unroll
            for (int nt = 0; nt < 4; ++nt) {
                short8 bf = *(short8*)&rs[wg][SW(nt * 16 + q16, ksp * 4 + quad)];
                acc[nt] = __builtin_amdgcn_mfma_f32_16x16x32_bf16(a, bf, acc[nt], 0, 0, 0);
            }
        }
    }

    // combine halves: half1 -> LDS (alias xs region), half0 adds + writes
    __syncthreads();
    float* poc = (float*)xs;   // 64*64 fp32 = 16 KB
    if (wg == 1) {
        #pragma unroll
        for (int nt = 0; nt < 4; ++nt)
            #pragma unroll
            for (int r = 0; r < 4; ++r)
                poc[(wq * 16 + quad * 4 + r) * 64 + nt * 16 + q16] = acc[nt][r];
    }
    __syncthreads();
    if (wg == 0) {
        #pragma unroll
        for (int nt = 0; nt < 4; ++nt)
            #pragma unroll
            for (int r = 0; r < 4; ++r) {
                int row = row0 + wq * 16 + quad * 4 + r;
                int col = nt * 16 + q16;
                float v = acc[nt][r] + poc[(wq * 16 + quad * 4 + r) * 64 + col];
                if (col == 63) v = x[(size_t)row * XROW + SEQ];
                av[(size_t)row * EMB + col] = v;
            }
    }
}

// ---------------------------------------------------------------------------
// qkv via MFMA: Qb/Kb bf16 [b][s][64], Vt bf16 [b][64][4096].
// 64 rows/block, 4 waves x 16 rows; weights staged transposed in LDS.
// ---------------------------------------------------------------------------
__global__ __launch_bounds__(256) void qkv_mfma(const float* __restrict__ av,
        const float* __restrict__ qw, const float* __restrict__ kw,
        const float* __restrict__ vw, ushort_t* __restrict__ Qb,
        ushort_t* __restrict__ Kb, ushort_t* __restrict__ Vt) {
    __shared__ ushort_t avs[64 * 64];
    __shared__ ushort_t wqs[64 * 64], wks[64 * 64], wvs[64 * 64];  // [e_out][k]
    const int tid = threadIdx.x;
    const int row0 = blockIdx.x * 64;
    const int w = tid >> 6, l = tid & 63;
    const int srow = tid >> 2, sc = (tid & 3) * 16;
    const int c0 = (tid & 3) * 2;

    {
        const float* ap = av + (size_t)(row0 + srow) * EMB + sc;
        alignas(16) ushort_t tmp[16];
        #pragma unroll
        for (int i = 0; i < 16; ++i) tmp[i] = f2bf(ap[i]);
        *(short8*)&avs[SW(srow, c0)]     = *(short8*)&tmp[0];
        *(short8*)&avs[SW(srow, c0 + 1)] = *(short8*)&tmp[8];
    }
    {
        alignas(16) ushort_t tq[16], tk[16], tv[16];
        #pragma unroll
        for (int i = 0; i < 16; ++i) {
            int kk = sc + i;
            tq[i] = f2bf(qw[kk * 64 + srow]);
            tk[i] = f2bf(kw[kk * 64 + srow]);
            tv[i] = f2bf(vw[kk * 64 + srow]);
        }
        *(short8*)&wqs[SW(srow, c0)]     = *(short8*)&tq[0];
        *(short8*)&wqs[SW(srow, c0 + 1)] = *(short8*)&tq[8];
        *(short8*)&wks[SW(srow, c0)]     = *(short8*)&tk[0];
        *(short8*)&wks[SW(srow, c0 + 1)] = *(short8*)&tk[8];
        *(short8*)&wvs[SW(srow, c0)]     = *(short8*)&tv[0];
        *(short8*)&wvs[SW(srow, c0 + 1)] = *(short8*)&tv[8];
    }
    __syncthreads();

    floatx4 aq[4], ak[4], avv[4];
    #pragma unroll
    for (int i = 0; i < 4; ++i) {
        aq[i] = (floatx4){0.f, 0.f, 0.f, 0.f};
        ak[i] = aq[i]; avv[i] = aq[i];
    }
    #pragma unroll
    for (int ksp = 0; ksp < 2; ++ksp) {
        short8 a = *(short8*)&avs[SW(w * 16 + (l & 15), ksp * 4 + (l >> 4))];
        #pragma unroll
        for (int nt = 0; nt < 4; ++nt) {
            int bo = SW(nt * 16 + (l & 15), ksp * 4 + (l >> 4));
            aq[nt]  = __builtin_amdgcn_mfma_f32_16x16x32_bf16(a, *(short8*)&wqs[bo], aq[nt], 0, 0, 0);
            ak[nt]  = __builtin_amdgcn_mfma_f32_16x16x32_bf16(a, *(short8*)&wks[bo], ak[nt], 0, 0, 0);
            avv[nt] = __builtin_amdgcn_mfma_f32_16x16x32_bf16(a, *(short8*)&wvs[bo], avv[nt], 0, 0, 0);
        }
    }

    const int b = row0 >> 12;
    #pragma unroll
    for (int nt = 0; nt < 4; ++nt)
        #pragma unroll
        for (int r = 0; r < 4; ++r) {
            int row = row0 + w * 16 + (l >> 4) * 4 + r;
            int col = nt * 16 + (l & 15);
            size_t o = (size_t)row * EMB + col;
            Qb[o] = f2bf(aq[nt][r]);
            Kb[o] = f2bf(ak[nt][r]);
            Vt[((size_t)b * EMB + col) * SEQ + (row & 4095)] = f2bf(avv[nt][r]);
        }
}

// ---------------------------------------------------------------------------
// MFMA flash attention, S^T form, no-max streaming softmax, split-K waves.
// 512 threads: wave-group wg handles K-half wg*2048..+2048; partial O,l
// combined through LDS at the end.  P round-trip: swizzled ds_write_b64.
// ---------------------------------------------------------------------------
__global__ __launch_bounds__(512) void flash_mfma(const ushort_t* __restrict__ Qb,
        const ushort_t* __restrict__ Kb, const ushort_t* __restrict__ Vt,
        float* __restrict__ out) {
    __shared__ ushort_t ks[2][64 * 64];     // per-half [kr][e] (swizzled)
    __shared__ ushort_t vt[2][64 * 64];     // per-half [e][kr] (swizzled)
    __shared__ ushort_t psbuf[8 * 1024];    // per-wave P [q][k] swizzled; reused as oc
    __shared__ float lrow[2][64];
    const int tid = threadIdx.x;
    const int w = tid >> 6, l = tid & 63;
    const int wg = w >> 2, wq = w & 3;
    const int quad = l >> 4, q16 = l & 15;
    const int b = blockIdx.y;
    const int q0 = blockIdx.x * 64;
    const size_t base  = (size_t)b * SEQ * EMB;
    const size_t vbase = (size_t)b * EMB * SEQ;
    const int t4 = tid & 255;
    const int srow = t4 >> 2, sc = (t4 & 3) * 16;
    const int c0 = (t4 & 3) * 2;
    const int kbase = wg * 2048;
    ushort_t* ps = &psbuf[w * 1024];

    // Q fragment: lane q16 holds row q0+wq*16+q16, 8 e per ksp
    short8 qf[2];
    #pragma unroll
    for (int ksp = 0; ksp < 2; ++ksp)
        qf[ksp] = *(const short8*)&Qb[base + (size_t)(q0 + wq * 16 + q16) * EMB
                                      + ksp * 32 + quad * 8];

    // prefetch tile 0 of this half
    short8 pk0, pk1, pv0, pv1;
    {
        const ushort_t* kp = Kb + base + (size_t)(kbase + srow) * EMB + sc;
        pk0 = *(const short8*)kp;
        pk1 = *(const short8*)(kp + 8);
        const ushort_t* vp = Vt + vbase + (size_t)srow * SEQ + kbase + sc;
        pv0 = *(const short8*)vp;
        pv1 = *(const short8*)(vp + 8);
    }

    floatx4 o_acc[4];
    #pragma unroll
    for (int i = 0; i < 4; ++i) o_acc[i] = (floatx4){0.f, 0.f, 0.f, 0.f};
    float lpart = 0.f;

    for (int kt0 = 0; kt0 < 2048; kt0 += 64) {
        __syncthreads();
        *(short8*)&ks[wg][SW(srow, c0)]     = pk0;
        *(short8*)&ks[wg][SW(srow, c0 + 1)] = pk1;
        *(short8*)&vt[wg][SW(srow, c0)]     = pv0;
        *(short8*)&vt[wg][SW(srow, c0 + 1)] = pv1;
        __syncthreads();
        if (kt0 + 64 < 2048) {
            const ushort_t* kp = Kb + base + (size_t)(kbase + kt0 + 64 + srow) * EMB + sc;
            pk0 = *(const short8*)kp;
            pk1 = *(const short8*)(kp + 8);
            const ushort_t* vp = Vt + vbase + (size_t)srow * SEQ + kbase + kt0 + 64 + sc;
            pv0 = *(const short8*)vp;
            pv1 = *(const short8*)(vp + 8);
        }

        // S^T = K Q^T : per nt, rows = k-local nt*16.., cols = q
        floatx4 s[4];
        #pragma unroll
        for (int nt = 0; nt < 4; ++nt) s[nt] = (floatx4){0.f, 0.f, 0.f, 0.f};
        #pragma unroll
        for (int ksp = 0; ksp < 2; ++ksp)
            #pragma unroll
            for (int nt = 0; nt < 4; ++nt) {
                short8 a = *(short8*)&ks[wg][SW(nt * 16 + q16, ksp * 4 + quad)];
                s[nt] = __builtin_amdgcn_mfma_f32_16x16x32_bf16(a, qf[ksp], s[nt], 0, 0, 0);
            }

        // exp; lane q = q16 fixed, k = nt*16+quad*4+r (4 consecutive per nt)
        #pragma unroll
        for (int nt = 0; nt < 4; ++nt) {
            float p0 = __expf(s[nt][0]);
            float p1 = __expf(s[nt][1]);
            float p2 = __expf(s[nt][2]);
            float p3 = __expf(s[nt][3]);
            lpart += (p0 + p1) + (p2 + p3);
            int g = nt * 4 + quad;                       // k-group (4 bf16 each)
            *(uint2*)&ps[q16 * 64 + ((g ^ q16) & 15) * 4] = pack4bf(p0, p1, p2, p3);
        }
        asm volatile("s_waitcnt lgkmcnt(0)" ::: "memory");

        // O += P V : A = P (lane m=q16 holds k=ksp*32+quad*8..+8), B = V
        #pragma unroll
        for (int ksp = 0; ksp < 2; ++ksp) {
            int g0 = ksp * 8 + quad * 2;
            uint2 a0 = *(uint2*)&ps[q16 * 64 + ((g0 ^ q16) & 15) * 4];
            uint2 a1 = *(uint2*)&ps[q16 * 64 + (((g0 + 1) ^ q16) & 15) * 4];
            U8 af;
            af.u.x = a0.x; af.u.y = a0.y; af.u.z = a1.x; af.u.w = a1.y;
            #pragma unroll
            for (int nt = 0; nt < 4; ++nt) {
                short8 bf = *(short8*)&vt[wg][SW(nt * 16 + q16, ksp * 4 + quad)];
                o_acc[nt] = __builtin_amdgcn_mfma_f32_16x16x32_bf16(af.s8, bf, o_acc[nt], 0, 0, 0);
            }
        }
    }

    // l: reduce over quads (lanes sharing q16)
    lpart += __shfl_xor(lpart, 16);
    lpart += __shfl_xor(lpart, 32);
    __syncthreads();                       // all waves done with psbuf
    if (quad == 0) lrow[wg][wq * 16 + q16] = lpart;
    float* oc = (float*)psbuf;             // 64x64 fp32 = 16 KB
    if (wg == 1) {
        #pragma unroll
        for (int nt = 0; nt < 4; ++nt)
            #pragma unroll
            for (int r = 0; r < 4; ++r)
                oc[(wq * 16 + quad * 4 + r) * 64 + nt * 16 + q16] = o_acc[nt][r];
    }
    __syncthreads();
    if (wg == 0) {
        float linv[4];
        #pragma unroll
        for (int r = 0; r < 4; ++r) {
            int q = wq * 16 + quad * 4 + r;
            linv[r] = 1.f / (lrow[0][q] + lrow[1][q]);
        }
        #pragma unroll
        for (int nt = 0; nt < 4; ++nt)
            #pragma unroll
            for (int r = 0; r < 4; ++r) {
                int row = q0 + wq * 16 + quad * 4 + r;
                int col = nt * 16 + q16;
                float v = (o_acc[nt][r] + oc[(wq * 16 + quad * 4 + r) * 64 + col]) * linv[r];
                out[base + (size_t)row * EMB + col] = v;
            }
    }
}

// ---------------------------------------------------------------------------
// Final contraction: out[b] += sum av[b,s,e]*coeffs[s,e]  (out pre-init'd)
// 256 x-blocks per batch so the grid fills all 256 CUs.
// ---------------------------------------------------------------------------
__global__ __launch_bounds__(256) void reduce_kernel(const float* __restrict__ av,
        const float* __restrict__ coeffs, float* __restrict__ out) {
    const int b = blockIdx.y;
    const size_t base = (size_t)b * SEQ * EMB;
    const int local0 = blockIdx.x * 4096;    // 64 x-blocks x 4096 floats
    const int tid = threadIdx.x;
    float ssum = 0.f;
    #pragma unroll
    for (int i = 0; i < 4; ++i) {
        int idx = local0 + (tid + i * 256) * 4;
        float4 a = *(const float4*)&av[base + idx];
        float4 c = *(const float4*)&coeffs[idx];
        ssum += a.x * c.x + a.y * c.y + a.z * c.z + a.w * c.w;
    }
    #pragma unroll
    for (int off = 1; off < 64; off <<= 1) ssum += __shfl_xor(ssum, off);
    __shared__ float wsum[4];
    if ((tid & 63) == 0) wsum[tid >> 6] = ssum;
    __syncthreads();
    if (tid == 0)
        atomicAdd(&out[b], wsum[0] + wsum[1] + wsum[2] + wsum[3]);
}

// ---------------------------------------------------------------------------
extern "C" void kernel_launch(void* const* d_in, const int* in_sizes, int n_in,
                              void* d_out, int out_size, void* d_ws, size_t ws_size,
                              hipStream_t stream) {
    const float* x      = (const float*)d_in[0];
    const float* q_ws   = (const float*)d_in[1];
    const float* k_ws   = (const float*)d_in[2];
    const float* v_ws   = (const float*)d_in[3];
    const float* rm     = (const float*)d_in[4];
    const float* coeffs = (const float*)d_in[5];
    const float* offset = (const float*)d_in[6];
    float* out = (float*)d_out;
    char* ws = (char*)d_ws;

    float*    AV  = (float*)ws;                          // 4 MB fp32
    ushort_t* Qb  = (ushort_t*)(ws + 4 * 1024 * 1024);   // 2 MB bf16
    ushort_t* Kb  = (ushort_t*)(ws + 6 * 1024 * 1024);   // 2 MB bf16
    ushort_t* Vt  = (ushort_t*)(ws + 8 * 1024 * 1024);   // 2 MB bf16
    ushort_t* rmT = (ushort_t*)(ws + 10 * 1024 * 1024);  // 0.5 MB bf16

    prep_rmt<<<256, 256, 0, stream>>>(rm, rmT, out, offset);
    proj_mfma<<<256, 512, 0, stream>>>(x, rmT, AV);
    for (int layer = 0; layer < 3; ++layer) {
        qkv_mfma<<<256, 256, 0, stream>>>(AV, q_ws + layer * 4096,
                                          k_ws + layer * 4096, v_ws + layer * 4096,
                                          Qb, Kb, Vt);
        flash_mfma<<<dim3(64, NB), 512, 0, stream>>>(Qb, Kb, Vt, AV);
    }
    reduce_kernel<<<dim3(64, NB), 256, 0, stream>>>(AV, coeffs, out);
}